// Round 14
// baseline (435.220 us; speedup 1.0000x reference)
//
#include <hip/hip_runtime.h>
#include <stdint.h>

#define AS1 __attribute__((address_space(1)))
#define AS3 __attribute__((address_space(3)))

typedef float v4f __attribute__((ext_vector_type(4)));
typedef __bf16 v8bf __attribute__((ext_vector_type(8)));
typedef __bf16 bf16x4 __attribute__((ext_vector_type(4)));

static_assert(sizeof(v8bf) == 16, "v8bf must be 16B");
static_assert(sizeof(bf16x4) == 8, "bf16x4 must be 8B");

__device__ __forceinline__ unsigned short f2bf(float f) {
  unsigned int x = __float_as_uint(f);
  x += 0x7fffu + ((x >> 16) & 1u);
  return (unsigned short)(x >> 16);
}

__device__ __forceinline__ float bf2f(unsigned short u) {
  return __uint_as_float((unsigned int)u << 16);
}

__device__ __forceinline__ void async16(void* lds, const void* g) {
  __builtin_amdgcn_global_load_lds((const AS1 unsigned int*)g,
                                   (AS3 unsigned int*)lds, 16, 0, 0);
}

// ---------------- prep kernels ----------------

// M = 0.99*I - 0.001*(W_e + W_e^T); m3 = M^3  (64 floats)
__global__ void prep_m3_kernel(const float* __restrict__ We, float* __restrict__ m3) {
  __shared__ float Ms[64], M2[64];
  int t = threadIdx.x;        // 64 threads
  int i = t >> 3, j = t & 7;
  float wsym = We[i * 8 + j] + We[j * 8 + i];
  Ms[t] = (i == j ? 0.99f : 0.0f) - 0.001f * wsym;
  __syncthreads();
  float s = 0.f;
#pragma unroll
  for (int p = 0; p < 8; ++p) s += Ms[i * 8 + p] * Ms[p * 8 + j];
  M2[t] = s;
  __syncthreads();
  s = 0.f;
#pragma unroll
  for (int p = 0; p < 8; ++p) s += M2[i * 8 + p] * Ms[p * 8 + j];
  m3[t] = s;
}

// f32 -> bf16 elementwise, 8 elems/thread
__global__ void cvt_bf16_kernel(const float* __restrict__ in, unsigned short* __restrict__ out) {
  int i = (blockIdx.x * 256 + threadIdx.x) * 8;
  float4 a = *(const float4*)(in + i);
  float4 b = *(const float4*)(in + i + 4);
  alignas(16) unsigned short r[8] = {f2bf(a.x), f2bf(a.y), f2bf(a.z), f2bf(a.w),
                                     f2bf(b.x), f2bf(b.y), f2bf(b.z), f2bf(b.w)};
  *(uint4*)(out + i) = *(const uint4*)r;
}

// In-place blade fold: h[g*8+j] = sum_p h_pre[g*8+p] * m3[p][j]
__global__ void fold_h_kernel(unsigned short* __restrict__ h, const float* __restrict__ m3) {
  __shared__ float m3s[64];
  int t = threadIdx.x;
  if (t < 64) m3s[t] = m3[t];
  __syncthreads();
  size_t g = ((size_t)blockIdx.x * 256 + t) * 8;
  uint4 raw = *(const uint4*)(h + g);
  const unsigned short* rp = (const unsigned short*)&raw;
  float v[8];
#pragma unroll
  for (int p = 0; p < 8; ++p) v[p] = bf2f(rp[p]);
  alignas(16) unsigned short o[8];
#pragma unroll
  for (int j = 0; j < 8; ++j) {
    float s = 0.f;
#pragma unroll
    for (int p = 0; p < 8; ++p) s += v[p] * m3s[p * 8 + j];
    o[j] = f2bf(s);
  }
  *(uint4*)(h + g) = *(const uint4*)o;
}

// ------- 256x256 GEMM, fused f32->bf16 transposed B-staging, counted-wait
//         single-region schedule (R10 base; CVT writes issued AFTER the 24
//         reads but INSIDE the MFMA region, so the exit lgkmcnt(0) is free
//         and write service hides under the MFMA stretch). A-halves use
//         DISTINCT register arrays a0/a1 (R13's overwrite bug fixed). -------
// C[M][N] = A[M][K] @ Bsrc[K][N] (+bias). A bf16 (k-contig, row stride ldkA);
// Bsrc f32 row-major (row stride ldnB), transposed+converted into LDS on the
// fly. SPLITK: blockIdx.z = K-chunk, bf16 partial out, no bias.
// 512 threads = 8 waves (2 M x 4 N); wave tile 128x64; BK=64.
// LDS 128KB: 2 x (A[256][64] | B[256][64]) bf16; elem (r,k) at byte
// r*128 + (((k>>3) ^ (r&7))<<4) + (k&7)*2.
// Per tile (single region, ONE barrier, counted waits):
//   STAGE_A(ob)                      <- 4 gload_lds for A(t+1)
//   [sched_barrier 0]
//   24 ds_reads (a0, b0r, b1r, a1)   <- lgkm queue head = reads only
//   [sched_barrier 0xF: VALU/SALU/MFMA may cross; DS may NOT]
//   CVT_WRITE_B(ob) + 64 MFMA        <- writes ordered after reads (in-order
//                                       lgkm => MFMA gating counts reads only);
//                                       write service + cvt VALU hide in MFMAs
//   [sched_barrier 0]
//   LOAD_BGLB                        <- refill L with B(t+2), 8 f32x4 gloads
//   [sched_barrier 0]
//   s_waitcnt vmcnt(8) lgkmcnt(0)    <- FIFO drains the 4 A-stages, keeps the
//                                       8 fresh B-gloads in flight; lgkm ~ 0
//   s_barrier
template <bool OUT_BF16, bool SPLITK>
__global__ __launch_bounds__(512, 1) void gemm256f_kernel(
    const unsigned short* __restrict__ A, const float* __restrict__ Bsrc,
    const float* __restrict__ bias, void* __restrict__ Cout,
    int M, int N, int K, int ldkA, int ldnB) {
  __shared__ char ldsc[131072];

  const int flat = blockIdx.x + gridDim.x * (blockIdx.y + gridDim.y * blockIdx.z);
  const int xcd = flat & 7, idx = flat >> 3;   // 256 blocks total
  int bn, bm, bz;
  if (SPLITK) { bz = xcd; bn = idx & 7; bm = idx >> 3; }
  else        { bz = 0;   bn = xcd * 8 + (idx & 7); bm = idx >> 3; }
  const int m0 = bm * 256, n0 = bn * 256;
  const int kb = SPLITK ? bz * K : 0;

  const int t = threadIdx.x;
  const int lane = t & 63, w = t >> 6;
  const int wr = w >> 2, wn = w & 3;
  const int r16 = lane & 15, kc = lane >> 4;
  const int xorv = (r16 & 7) << 4;
  const int acol0 = (kc << 4) ^ xorv;               // kk=0 byte col
  const int acol1 = ((4 | kc) << 4) ^ xorv;         // kk=1 byte col
  const int abase = wr * 16384 + r16 * 128;         // A region row base
  const int bbase = 32768 + wn * 8192 + r16 * 128;  // B region row base

  // A staging (global_load_lds, pre-swizzled source)
  const int srow = w * 8 + (lane >> 3);
  const int scol = ((lane & 7) ^ (lane >> 3)) * 8;
  const int sdst = w * 1024 + lane * 16;            // + i*8192 per issue
  const unsigned short* gAp = A + (size_t)(m0 + srow) * ldkA + kb + scol;

  // B staging (reg): wave w covers k-rows w*4..+3 (pass0), 32+w*4..+3 (pass1);
  // lane covers n = 4*lane..+3.
  const int n0s = 4 * lane;
  const int rotc = (lane >> 1) & 3;
  const float* gB = Bsrc + (size_t)(kb + w * 4) * ldnB + n0 + n0s;

  v4f acc[8][4];
#pragma unroll
  for (int mi = 0; mi < 8; ++mi)
#pragma unroll
    for (int nj = 0; nj < 4; ++nj) acc[mi][nj] = (v4f){0.f, 0.f, 0.f, 0.f};

  float4 L[2][4];

#define STAGE_A(OB)                                                        \
  _Pragma("unroll") for (int i = 0; i < 4; ++i)                            \
      async16(ldsc + (OB) + i * 8192 + sdst, gAp + (size_t)(i * 64) * ldkA);
#define LOAD_BGLB()                                                        \
  _Pragma("unroll") for (int ii = 0; ii < 2; ++ii)                         \
      _Pragma("unroll") for (int j = 0; j < 4; ++j)                        \
          L[ii][j] = *(const float4*)(gB + (size_t)(ii * 32 + j) * ldnB);
#define CVT_WRITE_B(OB)                                                          \
  _Pragma("unroll") for (int ii = 0; ii < 2; ++ii) {                             \
    const int k4 = w * 4 + ii * 32;                                              \
    bf16x4 R0 = (bf16x4){(__bf16)L[ii][0].x, (__bf16)L[ii][1].x,                 \
                         (__bf16)L[ii][2].x, (__bf16)L[ii][3].x};                \
    bf16x4 R1 = (bf16x4){(__bf16)L[ii][0].y, (__bf16)L[ii][1].y,                 \
                         (__bf16)L[ii][2].y, (__bf16)L[ii][3].y};                \
    bf16x4 R2 = (bf16x4){(__bf16)L[ii][0].z, (__bf16)L[ii][1].z,                 \
                         (__bf16)L[ii][2].z, (__bf16)L[ii][3].z};                \
    bf16x4 R3 = (bf16x4){(__bf16)L[ii][0].w, (__bf16)L[ii][1].w,                 \
                         (__bf16)L[ii][2].w, (__bf16)L[ii][3].w};                \
    _Pragma("unroll") for (int d = 0; d < 4; ++d) {                              \
      int o = (d + rotc) & 3;                                                    \
      int row = n0s + o;                                                         \
      bf16x4 vv = (o & 2) ? ((o & 1) ? R3 : R2) : ((o & 1) ? R1 : R0);           \
      *(bf16x4*)(ldsc + (OB) + 32768 + row * 128 +                               \
                 ((((k4 >> 3) ^ (row & 7)) << 4) | ((k4 & 7) << 1))) = vv;       \
    }                                                                            \
  }
#define LOAD_A(BB, MH, AR)                                                 \
  _Pragma("unroll") for (int m = 0; m < 4; ++m) {                          \
    AR[m * 2 + 0] = *(const v8bf*)(ldsc + (BB) + abase + (MH) * 8192 + m * 2048 + acol0); \
    AR[m * 2 + 1] = *(const v8bf*)(ldsc + (BB) + abase + (MH) * 8192 + m * 2048 + acol1); \
  }
#define LOAD_B(BB, NH, BR)                                                 \
  _Pragma("unroll") for (int n = 0; n < 2; ++n) {                          \
    BR[n * 2 + 0] = *(const v8bf*)(ldsc + (BB) + bbase + (NH) * 4096 + n * 2048 + acol0); \
    BR[n * 2 + 1] = *(const v8bf*)(ldsc + (BB) + bbase + (NH) * 4096 + n * 2048 + acol1); \
  }
#define MFMA_QUAD(MH, NH, AR, BR)                                          \
  _Pragma("unroll") for (int m = 0; m < 4; ++m) {                          \
    _Pragma("unroll") for (int n = 0; n < 2; ++n) {                        \
      acc[(MH) * 4 + m][(NH) * 2 + n] = __builtin_amdgcn_mfma_f32_16x16x32_bf16( \
          AR[m * 2 + 0], BR[n * 2 + 0], acc[(MH) * 4 + m][(NH) * 2 + n], 0, 0, 0); \
      acc[(MH) * 4 + m][(NH) * 2 + n] = __builtin_amdgcn_mfma_f32_16x16x32_bf16( \
          AR[m * 2 + 1], BR[n * 2 + 1], acc[(MH) * 4 + m][(NH) * 2 + n], 0, 0, 0); \
    }                                                                      \
  }

  const int NT = K >> 6;

  // ---- prologue: A(t0)+B(t0) staged into buf0; L holds B(t1) ----
  STAGE_A(0);               // A(t0): issued FIRST (FIFO head)
  LOAD_BGLB();              // L = B(t0)
  gAp += 64;                // -> A(t1)
  CVT_WRITE_B(0);           // waits B(t0) gloads -> FIFO also drains A-stages
  if (NT > 1) gB += (size_t)64 * ldnB;   // -> t1
  LOAD_BGLB();              // L = B(t1)
  if (NT > 2) gB += (size_t)64 * ldnB;   // -> t2
  asm volatile("s_waitcnt lgkmcnt(0)" ::: "memory");  // CVT writes landed
  __builtin_amdgcn_s_barrier();

  int buf = 0;
  for (int tt = 0; tt < NT; ++tt) {
    const int bb = buf << 16;
    const int ob = (buf ^ 1) << 16;
    const bool pf = (tt + 1 < NT);

    // head: next-tile A stage only (pure VMEM issue, full-region cover)
    if (pf) { STAGE_A(ob); gAp += 64; }
    __builtin_amdgcn_sched_barrier(0);

    // compute region: all 24 ds_reads first (distinct a0/a1 arrays — no
    // overwrite); then (DS may not cross the typed barrier) CVT writes +
    // 64 MFMA. MFMA lgkm-gating counts reads only; write service + cvt
    // VALU hide under the MFMA stretch.
    {
      v8bf a0[8], a1[8], b0r[4], b1r[4];
      LOAD_A(bb, 0, a0);
      LOAD_B(bb, 0, b0r);
      LOAD_B(bb, 1, b1r);
      LOAD_A(bb, 1, a1);
      __builtin_amdgcn_sched_barrier(0xF);  // ALU|VALU|SALU|MFMA may cross
      if (pf) { CVT_WRITE_B(ob); }
      MFMA_QUAD(0, 0, a0, b0r);
      MFMA_QUAD(0, 1, a0, b1r);
      MFMA_QUAD(1, 1, a1, b1r);
      MFMA_QUAD(1, 0, a1, b0r);
    }
    __builtin_amdgcn_sched_barrier(0);

    // tail: refill L with B(t+2) (WAR on L after CVT consumed it)
    LOAD_BGLB();
    if (tt + 3 < NT) gB += (size_t)64 * ldnB;
    __builtin_amdgcn_sched_barrier(0);

    // exit: FIFO-drain the 4 tile-old A-stages (vmcnt 4A+8B -> 8), keep the
    // 8 fresh B-gloads in flight; lgkm drained long ago (writes hidden).
    asm volatile("s_waitcnt vmcnt(8) lgkmcnt(0)" ::: "memory");
    __builtin_amdgcn_s_barrier();
    buf ^= 1;
  }

  unsigned short* Pp =
      (unsigned short*)Cout + (SPLITK ? (size_t)bz * M * N : 0);
#pragma unroll
  for (int mi = 0; mi < 8; ++mi) {
    int grow = m0 + wr * 128 + mi * 16 + kc * 4;
#pragma unroll
    for (int nj = 0; nj < 4; ++nj) {
      int gcol = n0 + wn * 64 + nj * 16 + r16;
      float bv = SPLITK ? 0.f : bias[gcol];
#pragma unroll
      for (int j = 0; j < 4; ++j) {
        float v = acc[mi][nj][j] + bv;
        size_t idxo = (size_t)(grow + j) * N + gcol;
        if (OUT_BF16)
          ((unsigned short*)Cout)[idxo] = f2bf(v);
        else if (SPLITK)
          Pp[idxo] = f2bf(v);            // bf16 partial
        else
          ((float*)Cout)[idxo] = v;
      }
    }
  }
#undef STAGE_A
#undef LOAD_BGLB
#undef CVT_WRITE_B
#undef LOAD_A
#undef LOAD_B
#undef MFMA_QUAD
}

// out[i] = sum_s bf16 part[s*MN + i] + bias[i % N], 4 elems/thread, fixed order
__global__ void reduce_splitk_kernel(const unsigned short* __restrict__ part,
                                     const float* __restrict__ bias,
                                     float* __restrict__ out, int MN, int N, int S) {
  int i = (blockIdx.x * 256 + threadIdx.x) * 4;
  float4 s = {0.f, 0.f, 0.f, 0.f};
  for (int k = 0; k < S; ++k) {
    ushort4 v = *(const ushort4*)(part + (size_t)k * MN + i);
    s.x += bf2f(v.x); s.y += bf2f(v.y); s.z += bf2f(v.z); s.w += bf2f(v.w);
  }
  int n = i & (N - 1);
  const float4 bv = *(const float4*)(bias + n);
  s.x += bv.x; s.y += bv.y; s.z += bv.z; s.w += bv.w;
  *(float4*)(out + i) = s;
}

// ---------------- launch ----------------

extern "C" void kernel_launch(void* const* d_in, const int* in_sizes, int n_in,
                              void* d_out, int out_size, void* d_ws, size_t ws_size,
                              hipStream_t stream) {
  const float* x     = (const float*)d_in[0];   // 1024 x 4096
  const float* W_in  = (const float*)d_in[1];   // 4096 x 16384
  const float* b_in  = (const float*)d_in[2];   // 16384
  const float* W_e   = (const float*)d_in[3];   // 8 x 8
  const float* W_out = (const float*)d_in[4];   // 16384 x 2048
  const float* b_out = (const float*)d_in[5];   // 2048
  float* out = (float*)d_out;                   // 1024 x 2048 f32

  char* ws = (char*)d_ws;
  const size_t OFF_M3 = 0;                      // 256 B
  const size_t OFF_X  = 1ull << 20;             // 8 MB   (x bf16)
  const size_t OFF_H  = 10ull << 20;            // 32 MB  (h bf16)
  const size_t OFF_P  = 48ull << 20;            // 32 MB  split-K bf16 partials
  float* m3          = (float*)(ws + OFF_M3);
  unsigned short* xb = (unsigned short*)(ws + OFF_X);
  unsigned short* h  = (unsigned short*)(ws + OFF_H);
  unsigned short* part = (unsigned short*)(ws + OFF_P);

  prep_m3_kernel<<<1, 64, 0, stream>>>(W_e, m3);
  cvt_bf16_kernel<<<2048, 256, 0, stream>>>(x, xb);  // 1024*4096 / (256*8)

  // h_pre = x @ W_in + b_in   (1024 x 16384, bf16 out; W staged f32->bf16 in-kernel)
  gemm256f_kernel<true, false><<<dim3(64, 4), 512, 0, stream>>>(
      xb, W_in, b_in, h, 1024, 16384, 4096, 4096, 16384);

  // h = h_pre * (I (x) M^3)  (in-place blade fold)
  fold_h_kernel<<<8192, 256, 0, stream>>>(h, m3);

  // partials[z] = h @ W_out over K-chunk z  (split-K 8 x 2048, bf16 partials)
  gemm256f_kernel<false, true><<<dim3(8, 4, 8), 512, 0, stream>>>(
      h, W_out, nullptr, part, 1024, 2048, 2048, 16384, 2048);

  // out = sum_z partials[z] + b_out
  reduce_splitk_kernel<<<2048, 256, 0, stream>>>(part, b_out, out, 1024 * 2048, 2048, 8);
}

// Round 15
// 238.610 us; speedup vs baseline: 1.8240x; 1.8240x over previous
//
#include <hip/hip_runtime.h>
#include <stdint.h>

#define AS1 __attribute__((address_space(1)))
#define AS3 __attribute__((address_space(3)))

typedef float v4f __attribute__((ext_vector_type(4)));
typedef __bf16 v8bf __attribute__((ext_vector_type(8)));
typedef __bf16 bf16x4 __attribute__((ext_vector_type(4)));

static_assert(sizeof(v8bf) == 16, "v8bf must be 16B");
static_assert(sizeof(bf16x4) == 8, "bf16x4 must be 8B");

__device__ __forceinline__ unsigned short f2bf(float f) {
  unsigned int x = __float_as_uint(f);
  x += 0x7fffu + ((x >> 16) & 1u);
  return (unsigned short)(x >> 16);
}

__device__ __forceinline__ float bf2f(unsigned short u) {
  return __uint_as_float((unsigned int)u << 16);
}

__device__ __forceinline__ void async16(void* lds, const void* g) {
  __builtin_amdgcn_global_load_lds((const AS1 unsigned int*)g,
                                   (AS3 unsigned int*)lds, 16, 0, 0);
}

// ---------------- prep kernels ----------------

// M = 0.99*I - 0.001*(W_e + W_e^T); m3 = M^3  (64 floats)
__global__ void prep_m3_kernel(const float* __restrict__ We, float* __restrict__ m3) {
  __shared__ float Ms[64], M2[64];
  int t = threadIdx.x;        // 64 threads
  int i = t >> 3, j = t & 7;
  float wsym = We[i * 8 + j] + We[j * 8 + i];
  Ms[t] = (i == j ? 0.99f : 0.0f) - 0.001f * wsym;
  __syncthreads();
  float s = 0.f;
#pragma unroll
  for (int p = 0; p < 8; ++p) s += Ms[i * 8 + p] * Ms[p * 8 + j];
  M2[t] = s;
  __syncthreads();
  s = 0.f;
#pragma unroll
  for (int p = 0; p < 8; ++p) s += M2[i * 8 + p] * Ms[p * 8 + j];
  m3[t] = s;
}

// f32 -> bf16 elementwise, 8 elems/thread
__global__ void cvt_bf16_kernel(const float* __restrict__ in, unsigned short* __restrict__ out) {
  int i = (blockIdx.x * 256 + threadIdx.x) * 8;
  float4 a = *(const float4*)(in + i);
  float4 b = *(const float4*)(in + i + 4);
  alignas(16) unsigned short r[8] = {f2bf(a.x), f2bf(a.y), f2bf(a.z), f2bf(a.w),
                                     f2bf(b.x), f2bf(b.y), f2bf(b.z), f2bf(b.w)};
  *(uint4*)(out + i) = *(const uint4*)r;
}

// ------- 256x256 GEMM, fused f32->bf16 transposed B-staging, counted-wait
//         single-region schedule (R10 exact K-loop). FOLD: blade fold
//         (I (x) M^3) applied in the epilogue via the freed 128KB LDS,
//         replacing the separate fold_h pass. -------
// C[M][N] = A[M][K] @ Bsrc[K][N] (+bias). A bf16 (k-contig, row stride ldkA);
// Bsrc f32 row-major (row stride ldnB), transposed+converted into LDS on the
// fly. SPLITK: blockIdx.z = K-chunk, bf16 partial out, no bias.
// 512 threads = 8 waves (2 M x 4 N); wave tile 128x64; BK=64.
// LDS 128KB: 2 x (A[256][64] | B[256][64]) bf16; elem (r,k) at byte
// r*128 + (((k>>3) ^ (r&7))<<4) + (k&7)*2.
// Per tile (single region, ONE barrier, counted waits):
//   STAGE_A(ob); [SB]
//   24 ds_reads + 64 MFMA (reads-only lgkm queue, a[8] reused between halves
//   to keep VGPR<=128 — no spills); [SB]
//   tail: CVT_WRITE_B(ob) (consumes L, full-region cover) + LOAD_BGLB(t+2);
//   [SB]; s_waitcnt vmcnt(8) lgkmcnt(0); s_barrier.
// FOLD epilogue: acc+bias -> LDS bf16 [256 rows][512B]; barrier; each thread
// reads 16 blade-groups (uint4), folds with m3 (uniform->SGPR), coalesced
// global store (half-wave per row).
template <bool OUT_BF16, bool SPLITK, bool FOLD>
__global__ __launch_bounds__(512, 1) void gemm256f_kernel(
    const unsigned short* __restrict__ A, const float* __restrict__ Bsrc,
    const float* __restrict__ bias, void* __restrict__ Cout,
    int M, int N, int K, int ldkA, int ldnB, const float* __restrict__ m3) {
  __shared__ char ldsc[131072];

  const int flat = blockIdx.x + gridDim.x * (blockIdx.y + gridDim.y * blockIdx.z);
  const int xcd = flat & 7, idx = flat >> 3;   // 256 blocks total
  int bn, bm, bz;
  if (SPLITK) { bz = xcd; bn = idx & 7; bm = idx >> 3; }
  else        { bz = 0;   bn = xcd * 8 + (idx & 7); bm = idx >> 3; }
  const int m0 = bm * 256, n0 = bn * 256;
  const int kb = SPLITK ? bz * K : 0;

  const int t = threadIdx.x;
  const int lane = t & 63, w = t >> 6;
  const int wr = w >> 2, wn = w & 3;
  const int r16 = lane & 15, kc = lane >> 4;
  const int xorv = (r16 & 7) << 4;
  const int acol0 = (kc << 4) ^ xorv;               // kk=0 byte col
  const int acol1 = ((4 | kc) << 4) ^ xorv;         // kk=1 byte col
  const int abase = wr * 16384 + r16 * 128;         // A region row base
  const int bbase = 32768 + wn * 8192 + r16 * 128;  // B region row base

  // A staging (global_load_lds, pre-swizzled source)
  const int srow = w * 8 + (lane >> 3);
  const int scol = ((lane & 7) ^ (lane >> 3)) * 8;
  const int sdst = w * 1024 + lane * 16;            // + i*8192 per issue
  const unsigned short* gAp = A + (size_t)(m0 + srow) * ldkA + kb + scol;

  // B staging (reg): wave w covers k-rows w*4..+3 (pass0), 32+w*4..+3 (pass1);
  // lane covers n = 4*lane..+3.
  const int n0s = 4 * lane;
  const int rotc = (lane >> 1) & 3;
  const float* gB = Bsrc + (size_t)(kb + w * 4) * ldnB + n0 + n0s;

  v4f acc[8][4];
#pragma unroll
  for (int mi = 0; mi < 8; ++mi)
#pragma unroll
    for (int nj = 0; nj < 4; ++nj) acc[mi][nj] = (v4f){0.f, 0.f, 0.f, 0.f};

  float4 L[2][4];

#define STAGE_A(OB)                                                        \
  _Pragma("unroll") for (int i = 0; i < 4; ++i)                            \
      async16(ldsc + (OB) + i * 8192 + sdst, gAp + (size_t)(i * 64) * ldkA);
#define LOAD_BGLB()                                                        \
  _Pragma("unroll") for (int ii = 0; ii < 2; ++ii)                         \
      _Pragma("unroll") for (int j = 0; j < 4; ++j)                        \
          L[ii][j] = *(const float4*)(gB + (size_t)(ii * 32 + j) * ldnB);
#define CVT_WRITE_B(OB)                                                          \
  _Pragma("unroll") for (int ii = 0; ii < 2; ++ii) {                             \
    const int k4 = w * 4 + ii * 32;                                              \
    bf16x4 R0 = (bf16x4){(__bf16)L[ii][0].x, (__bf16)L[ii][1].x,                 \
                         (__bf16)L[ii][2].x, (__bf16)L[ii][3].x};                \
    bf16x4 R1 = (bf16x4){(__bf16)L[ii][0].y, (__bf16)L[ii][1].y,                 \
                         (__bf16)L[ii][2].y, (__bf16)L[ii][3].y};                \
    bf16x4 R2 = (bf16x4){(__bf16)L[ii][0].z, (__bf16)L[ii][1].z,                 \
                         (__bf16)L[ii][2].z, (__bf16)L[ii][3].z};                \
    bf16x4 R3 = (bf16x4){(__bf16)L[ii][0].w, (__bf16)L[ii][1].w,                 \
                         (__bf16)L[ii][2].w, (__bf16)L[ii][3].w};                \
    _Pragma("unroll") for (int d = 0; d < 4; ++d) {                              \
      int o = (d + rotc) & 3;                                                    \
      int row = n0s + o;                                                         \
      bf16x4 vv = (o & 2) ? ((o & 1) ? R3 : R2) : ((o & 1) ? R1 : R0);           \
      *(bf16x4*)(ldsc + (OB) + 32768 + row * 128 +                               \
                 ((((k4 >> 3) ^ (row & 7)) << 4) | ((k4 & 7) << 1))) = vv;       \
    }                                                                            \
  }
#define LOAD_A(BB, MH)                                                     \
  _Pragma("unroll") for (int m = 0; m < 4; ++m) {                          \
    a[m * 2 + 0] = *(const v8bf*)(ldsc + (BB) + abase + (MH) * 8192 + m * 2048 + acol0); \
    a[m * 2 + 1] = *(const v8bf*)(ldsc + (BB) + abase + (MH) * 8192 + m * 2048 + acol1); \
  }
#define LOAD_B(BB, NH, BR)                                                 \
  _Pragma("unroll") for (int n = 0; n < 2; ++n) {                          \
    BR[n * 2 + 0] = *(const v8bf*)(ldsc + (BB) + bbase + (NH) * 4096 + n * 2048 + acol0); \
    BR[n * 2 + 1] = *(const v8bf*)(ldsc + (BB) + bbase + (NH) * 4096 + n * 2048 + acol1); \
  }
#define MFMA_QUAD(MH, NH, BR)                                              \
  _Pragma("unroll") for (int m = 0; m < 4; ++m) {                          \
    _Pragma("unroll") for (int n = 0; n < 2; ++n) {                        \
      acc[(MH) * 4 + m][(NH) * 2 + n] = __builtin_amdgcn_mfma_f32_16x16x32_bf16( \
          a[m * 2 + 0], BR[n * 2 + 0], acc[(MH) * 4 + m][(NH) * 2 + n], 0, 0, 0); \
      acc[(MH) * 4 + m][(NH) * 2 + n] = __builtin_amdgcn_mfma_f32_16x16x32_bf16( \
          a[m * 2 + 1], BR[n * 2 + 1], acc[(MH) * 4 + m][(NH) * 2 + n], 0, 0, 0); \
    }                                                                      \
  }

  const int NT = K >> 6;

  // ---- prologue: A(t0)+B(t0) staged into buf0; L holds B(t1) ----
  STAGE_A(0);               // A(t0): issued FIRST (FIFO head)
  LOAD_BGLB();              // L = B(t0)
  gAp += 64;                // -> A(t1)
  CVT_WRITE_B(0);           // waits B(t0) gloads -> FIFO also drains A-stages
  if (NT > 1) gB += (size_t)64 * ldnB;   // -> t1
  LOAD_BGLB();              // L = B(t1)
  if (NT > 2) gB += (size_t)64 * ldnB;   // -> t2
  asm volatile("s_waitcnt lgkmcnt(0)" ::: "memory");  // CVT writes landed
  __builtin_amdgcn_s_barrier();

  int buf = 0;
  for (int tt = 0; tt < NT; ++tt) {
    const int bb = buf << 16;
    const int ob = (buf ^ 1) << 16;
    const bool pf = (tt + 1 < NT);

    // head: next-tile A stage only (pure VMEM issue, full-region cover)
    if (pf) { STAGE_A(ob); gAp += 64; }
    __builtin_amdgcn_sched_barrier(0);

    // compute region: 24 ds_reads + 64 MFMA. lgkm queue = reads only; a[8]
    // reused between halves (keeps VGPR<=128, no spill — R14 lesson).
    {
      v8bf a[8], b0r[4], b1r[4];
      LOAD_A(bb, 0);
      LOAD_B(bb, 0, b0r);
      LOAD_B(bb, 1, b1r);
      MFMA_QUAD(0, 0, b0r);
      MFMA_QUAD(0, 1, b1r);
      LOAD_A(bb, 1);
      MFMA_QUAD(1, 1, b1r);
      MFMA_QUAD(1, 0, b0r);
    }
    __builtin_amdgcn_sched_barrier(0);

    // tail: convert+write B(t+1) into ob (consumes L, loaded a full region
    // ago -> its vmcnt wait drains old B + A-stages cheaply), refill L.
    if (pf) { CVT_WRITE_B(ob); }
    LOAD_BGLB();
    if (tt + 3 < NT) gB += (size_t)64 * ldnB;
    __builtin_amdgcn_sched_barrier(0);

    // exit: FIFO-drain the 4 tile-old A-stages (vmcnt 4A+8B -> 8), keep the
    // 8 fresh B-gloads in flight; lgkm tail = just-issued CVT writes.
    asm volatile("s_waitcnt vmcnt(8) lgkmcnt(0)" ::: "memory");
    __builtin_amdgcn_s_barrier();
    buf ^= 1;
  }

  if (FOLD) {
    // ---- blade-fold epilogue via freed LDS (exactly 256x256 bf16 = 128KB).
    // 1) acc + bias -> LDS [row][col], row stride 512 B.
#pragma unroll
    for (int mi = 0; mi < 8; ++mi) {
      int lrow = wr * 128 + mi * 16 + kc * 4;
#pragma unroll
      for (int nj = 0; nj < 4; ++nj) {
        int lcol = wn * 64 + nj * 16 + r16;
        float bv = bias[n0 + lcol];
#pragma unroll
        for (int j = 0; j < 4; ++j)
          *(unsigned short*)(ldsc + (lrow + j) * 512 + lcol * 2) =
              f2bf(acc[mi][nj][j] + bv);
      }
    }
    __syncthreads();
    // 2) fold with m3 (uniform loads -> scalar regs) + coalesced store.
    //    Half-wave per row: lanes 0..31 -> row r cols 0..255 (32 x 8-col
    //    groups), lanes 32..63 -> row r+1.
    float m3r[64];
#pragma unroll
    for (int p = 0; p < 64; ++p) m3r[p] = m3[p];
    const int cg = (t & 31) * 8;           // group col
    const int rof = (t >> 5);              // 0..15
    unsigned short* ho = (unsigned short*)Cout;
#pragma unroll
    for (int pass = 0; pass < 16; ++pass) {
      int row = pass * 16 + rof;
      uint4 raw = *(const uint4*)(ldsc + row * 512 + cg * 2);
      const unsigned short* rp = (const unsigned short*)&raw;
      float v[8];
#pragma unroll
      for (int p = 0; p < 8; ++p) v[p] = bf2f(rp[p]);
      alignas(16) unsigned short o[8];
#pragma unroll
      for (int j = 0; j < 8; ++j) {
        float s = 0.f;
#pragma unroll
        for (int p = 0; p < 8; ++p) s += v[p] * m3r[p * 8 + j];
        o[j] = f2bf(s);
      }
      *(uint4*)(ho + (size_t)(m0 + row) * N + n0 + cg) = *(const uint4*)o;
    }
    return;
  }

  unsigned short* Pp =
      (unsigned short*)Cout + (SPLITK ? (size_t)bz * M * N : 0);
#pragma unroll
  for (int mi = 0; mi < 8; ++mi) {
    int grow = m0 + wr * 128 + mi * 16 + kc * 4;
#pragma unroll
    for (int nj = 0; nj < 4; ++nj) {
      int gcol = n0 + wn * 64 + nj * 16 + r16;
      float bv = SPLITK ? 0.f : bias[gcol];
#pragma unroll
      for (int j = 0; j < 4; ++j) {
        float v = acc[mi][nj][j] + bv;
        size_t idxo = (size_t)(grow + j) * N + gcol;
        if (OUT_BF16)
          ((unsigned short*)Cout)[idxo] = f2bf(v);
        else if (SPLITK)
          Pp[idxo] = f2bf(v);            // bf16 partial
        else
          ((float*)Cout)[idxo] = v;
      }
    }
  }
#undef STAGE_A
#undef LOAD_BGLB
#undef CVT_WRITE_B
#undef LOAD_A
#undef LOAD_B
#undef MFMA_QUAD
}

// out[i] = sum_s bf16 part[s*MN + i] + bias[i % N], 4 elems/thread, fixed order
__global__ void reduce_splitk_kernel(const unsigned short* __restrict__ part,
                                     const float* __restrict__ bias,
                                     float* __restrict__ out, int MN, int N, int S) {
  int i = (blockIdx.x * 256 + threadIdx.x) * 4;
  float4 s = {0.f, 0.f, 0.f, 0.f};
  for (int k = 0; k < S; ++k) {
    ushort4 v = *(const ushort4*)(part + (size_t)k * MN + i);
    s.x += bf2f(v.x); s.y += bf2f(v.y); s.z += bf2f(v.z); s.w += bf2f(v.w);
  }
  int n = i & (N - 1);
  const float4 bv = *(const float4*)(bias + n);
  s.x += bv.x; s.y += bv.y; s.z += bv.z; s.w += bv.w;
  *(float4*)(out + i) = s;
}

// ---------------- launch ----------------

extern "C" void kernel_launch(void* const* d_in, const int* in_sizes, int n_in,
                              void* d_out, int out_size, void* d_ws, size_t ws_size,
                              hipStream_t stream) {
  const float* x     = (const float*)d_in[0];   // 1024 x 4096
  const float* W_in  = (const float*)d_in[1];   // 4096 x 16384
  const float* b_in  = (const float*)d_in[2];   // 16384
  const float* W_e   = (const float*)d_in[3];   // 8 x 8
  const float* W_out = (const float*)d_in[4];   // 16384 x 2048
  const float* b_out = (const float*)d_in[5];   // 2048
  float* out = (float*)d_out;                   // 1024 x 2048 f32

  char* ws = (char*)d_ws;
  const size_t OFF_M3 = 0;                      // 256 B
  const size_t OFF_X  = 1ull << 20;             // 8 MB   (x bf16)
  const size_t OFF_H  = 10ull << 20;            // 32 MB  (h bf16)
  const size_t OFF_P  = 48ull << 20;            // 32 MB  split-K bf16 partials
  float* m3          = (float*)(ws + OFF_M3);
  unsigned short* xb = (unsigned short*)(ws + OFF_X);
  unsigned short* h  = (unsigned short*)(ws + OFF_H);
  unsigned short* part = (unsigned short*)(ws + OFF_P);

  prep_m3_kernel<<<1, 64, 0, stream>>>(W_e, m3);
  cvt_bf16_kernel<<<2048, 256, 0, stream>>>(x, xb);  // 1024*4096 / (256*8)

  // h = fold(x @ W_in + b_in)  (1024 x 16384, bf16; W staged f32->bf16 and
  // M^3 blade-fold applied in-epilogue)
  gemm256f_kernel<true, false, true><<<dim3(64, 4), 512, 0, stream>>>(
      xb, W_in, b_in, h, 1024, 16384, 4096, 4096, 16384, m3);

  // partials[z] = h @ W_out over K-chunk z  (split-K 8 x 2048, bf16 partials)
  gemm256f_kernel<false, true, false><<<dim3(8, 4, 8), 512, 0, stream>>>(
      h, W_out, nullptr, part, 1024, 2048, 2048, 16384, 2048, nullptr);

  // out = sum_z partials[z] + b_out
  reduce_splitk_kernel<<<2048, 256, 0, stream>>>(part, b_out, out, 1024 * 2048, 2048, 8);
}

// Round 16
// 230.918 us; speedup vs baseline: 1.8847x; 1.0333x over previous
//
#include <hip/hip_runtime.h>
#include <stdint.h>

#define AS1 __attribute__((address_space(1)))
#define AS3 __attribute__((address_space(3)))

typedef float v4f __attribute__((ext_vector_type(4)));
typedef __bf16 v8bf __attribute__((ext_vector_type(8)));
typedef __bf16 bf16x4 __attribute__((ext_vector_type(4)));

static_assert(sizeof(v8bf) == 16, "v8bf must be 16B");
static_assert(sizeof(bf16x4) == 8, "bf16x4 must be 8B");

__device__ __forceinline__ unsigned short f2bf(float f) {
  unsigned int x = __float_as_uint(f);
  x += 0x7fffu + ((x >> 16) & 1u);
  return (unsigned short)(x >> 16);
}

__device__ __forceinline__ float bf2f(unsigned short u) {
  return __uint_as_float((unsigned int)u << 16);
}

__device__ __forceinline__ void async16(void* lds, const void* g) {
  __builtin_amdgcn_global_load_lds((const AS1 unsigned int*)g,
                                   (AS3 unsigned int*)lds, 16, 0, 0);
}

// ---------------- prep kernels ----------------

// M = 0.99*I - 0.001*(W_e + W_e^T); m3 = M^3  (64 floats)
__global__ void prep_m3_kernel(const float* __restrict__ We, float* __restrict__ m3) {
  __shared__ float Ms[64], M2[64];
  int t = threadIdx.x;        // 64 threads
  int i = t >> 3, j = t & 7;
  float wsym = We[i * 8 + j] + We[j * 8 + i];
  Ms[t] = (i == j ? 0.99f : 0.0f) - 0.001f * wsym;
  __syncthreads();
  float s = 0.f;
#pragma unroll
  for (int p = 0; p < 8; ++p) s += Ms[i * 8 + p] * Ms[p * 8 + j];
  M2[t] = s;
  __syncthreads();
  s = 0.f;
#pragma unroll
  for (int p = 0; p < 8; ++p) s += M2[i * 8 + p] * Ms[p * 8 + j];
  m3[t] = s;
}

// f32 -> bf16 elementwise, 8 elems/thread
__global__ void cvt_bf16_kernel(const float* __restrict__ in, unsigned short* __restrict__ out) {
  int i = (blockIdx.x * 256 + threadIdx.x) * 8;
  float4 a = *(const float4*)(in + i);
  float4 b = *(const float4*)(in + i + 4);
  alignas(16) unsigned short r[8] = {f2bf(a.x), f2bf(a.y), f2bf(a.z), f2bf(a.w),
                                     f2bf(b.x), f2bf(b.y), f2bf(b.z), f2bf(b.w)};
  *(uint4*)(out + i) = *(const uint4*)r;
}

// ------- 256x256 GEMM, fused f32->bf16 transposed B-staging, counted-wait
//         single-region schedule. R16: CVT+BGLB moved BETWEEN the two MFMA
//         halves (code motion only — liveness identical to R10) so the CVT
//         ds_writes retire under the second MFMA stretch and the exit
//         lgkmcnt(0) is free. FOLD: blade fold (I (x) M^3) in the epilogue
//         via the freed 128KB LDS. -------
// C[M][N] = A[M][K] @ Bsrc[K][N] (+bias). A bf16 (k-contig, row stride ldkA);
// Bsrc f32 row-major (row stride ldnB), transposed+converted into LDS on the
// fly. SPLITK: blockIdx.z = K-chunk, bf16 partial out, no bias.
// 512 threads = 8 waves (2 M x 4 N); wave tile 128x64; BK=64.
// LDS 128KB: 2 x (A[256][64] | B[256][64]) bf16; elem (r,k) at byte
// r*128 + (((k>>3) ^ (r&7))<<4) + (k&7)*2.
// Per tile (ONE barrier, counted waits):
//   STAGE_A(ob)                       <- 4 gload_lds for A(t+1)
//   [SB0] reads a0,b0,b1 (16 ds) + MFMA(0,0),(0,1)
//   [SB0] LOAD_A(1) (8 ds reads, FIFO before writes)
//         CVT_WRITE_B(ob)             <- consumes L; implicit vmcnt(4) drains
//                                        the 8 tile-old B-gloads (A stays)
//         LOAD_BGLB                   <- refill L with B(t+2)
//   [SB0] MFMA(1,1),(1,0)             <- gate lgkmcnt(8): a1 reads done,
//                                        writes retire under these MFMAs
//   [SB0] s_waitcnt vmcnt(8) lgkmcnt(0)  <- drains 4 A-stages (FIFO oldest),
//                                        keeps 8 fresh B-gloads; lgkm ~free
//   s_barrier
template <bool OUT_BF16, bool SPLITK, bool FOLD>
__global__ __launch_bounds__(512, 1) void gemm256f_kernel(
    const unsigned short* __restrict__ A, const float* __restrict__ Bsrc,
    const float* __restrict__ bias, void* __restrict__ Cout,
    int M, int N, int K, int ldkA, int ldnB, const float* __restrict__ m3) {
  __shared__ char ldsc[131072];

  const int flat = blockIdx.x + gridDim.x * (blockIdx.y + gridDim.y * blockIdx.z);
  const int xcd = flat & 7, idx = flat >> 3;   // 256 blocks total
  int bn, bm, bz;
  if (SPLITK) { bz = xcd; bn = idx & 7; bm = idx >> 3; }
  else        { bz = 0;   bn = xcd * 8 + (idx & 7); bm = idx >> 3; }
  const int m0 = bm * 256, n0 = bn * 256;
  const int kb = SPLITK ? bz * K : 0;

  const int t = threadIdx.x;
  const int lane = t & 63, w = t >> 6;
  const int wr = w >> 2, wn = w & 3;
  const int r16 = lane & 15, kc = lane >> 4;
  const int xorv = (r16 & 7) << 4;
  const int acol0 = (kc << 4) ^ xorv;               // kk=0 byte col
  const int acol1 = ((4 | kc) << 4) ^ xorv;         // kk=1 byte col
  const int abase = wr * 16384 + r16 * 128;         // A region row base
  const int bbase = 32768 + wn * 8192 + r16 * 128;  // B region row base

  // A staging (global_load_lds, pre-swizzled source)
  const int srow = w * 8 + (lane >> 3);
  const int scol = ((lane & 7) ^ (lane >> 3)) * 8;
  const int sdst = w * 1024 + lane * 16;            // + i*8192 per issue
  const unsigned short* gAp = A + (size_t)(m0 + srow) * ldkA + kb + scol;

  // B staging (reg): wave w covers k-rows w*4..+3 (pass0), 32+w*4..+3 (pass1);
  // lane covers n = 4*lane..+3.
  const int n0s = 4 * lane;
  const int rotc = (lane >> 1) & 3;
  const float* gB = Bsrc + (size_t)(kb + w * 4) * ldnB + n0 + n0s;

  v4f acc[8][4];
#pragma unroll
  for (int mi = 0; mi < 8; ++mi)
#pragma unroll
    for (int nj = 0; nj < 4; ++nj) acc[mi][nj] = (v4f){0.f, 0.f, 0.f, 0.f};

  float4 L[2][4];

#define STAGE_A(OB)                                                        \
  _Pragma("unroll") for (int i = 0; i < 4; ++i)                            \
      async16(ldsc + (OB) + i * 8192 + sdst, gAp + (size_t)(i * 64) * ldkA);
#define LOAD_BGLB()                                                        \
  _Pragma("unroll") for (int ii = 0; ii < 2; ++ii)                         \
      _Pragma("unroll") for (int j = 0; j < 4; ++j)                        \
          L[ii][j] = *(const float4*)(gB + (size_t)(ii * 32 + j) * ldnB);
#define CVT_WRITE_B(OB)                                                          \
  _Pragma("unroll") for (int ii = 0; ii < 2; ++ii) {                             \
    const int k4 = w * 4 + ii * 32;                                              \
    bf16x4 R0 = (bf16x4){(__bf16)L[ii][0].x, (__bf16)L[ii][1].x,                 \
                         (__bf16)L[ii][2].x, (__bf16)L[ii][3].x};                \
    bf16x4 R1 = (bf16x4){(__bf16)L[ii][0].y, (__bf16)L[ii][1].y,                 \
                         (__bf16)L[ii][2].y, (__bf16)L[ii][3].y};                \
    bf16x4 R2 = (bf16x4){(__bf16)L[ii][0].z, (__bf16)L[ii][1].z,                 \
                         (__bf16)L[ii][2].z, (__bf16)L[ii][3].z};                \
    bf16x4 R3 = (bf16x4){(__bf16)L[ii][0].w, (__bf16)L[ii][1].w,                 \
                         (__bf16)L[ii][2].w, (__bf16)L[ii][3].w};                \
    _Pragma("unroll") for (int d = 0; d < 4; ++d) {                              \
      int o = (d + rotc) & 3;                                                    \
      int row = n0s + o;                                                         \
      bf16x4 vv = (o & 2) ? ((o & 1) ? R3 : R2) : ((o & 1) ? R1 : R0);           \
      *(bf16x4*)(ldsc + (OB) + 32768 + row * 128 +                               \
                 ((((k4 >> 3) ^ (row & 7)) << 4) | ((k4 & 7) << 1))) = vv;       \
    }                                                                            \
  }
#define LOAD_A(BB, MH)                                                     \
  _Pragma("unroll") for (int m = 0; m < 4; ++m) {                          \
    a[m * 2 + 0] = *(const v8bf*)(ldsc + (BB) + abase + (MH) * 8192 + m * 2048 + acol0); \
    a[m * 2 + 1] = *(const v8bf*)(ldsc + (BB) + abase + (MH) * 8192 + m * 2048 + acol1); \
  }
#define LOAD_B(BB, NH, BR)                                                 \
  _Pragma("unroll") for (int n = 0; n < 2; ++n) {                          \
    BR[n * 2 + 0] = *(const v8bf*)(ldsc + (BB) + bbase + (NH) * 4096 + n * 2048 + acol0); \
    BR[n * 2 + 1] = *(const v8bf*)(ldsc + (BB) + bbase + (NH) * 4096 + n * 2048 + acol1); \
  }
#define MFMA_QUAD(MH, NH, BR)                                              \
  _Pragma("unroll") for (int m = 0; m < 4; ++m) {                          \
    _Pragma("unroll") for (int n = 0; n < 2; ++n) {                        \
      acc[(MH) * 4 + m][(NH) * 2 + n] = __builtin_amdgcn_mfma_f32_16x16x32_bf16( \
          a[m * 2 + 0], BR[n * 2 + 0], acc[(MH) * 4 + m][(NH) * 2 + n], 0, 0, 0); \
      acc[(MH) * 4 + m][(NH) * 2 + n] = __builtin_amdgcn_mfma_f32_16x16x32_bf16( \
          a[m * 2 + 1], BR[n * 2 + 1], acc[(MH) * 4 + m][(NH) * 2 + n], 0, 0, 0); \
    }                                                                      \
  }

  const int NT = K >> 6;

  // ---- prologue: A(t0)+B(t0) staged into buf0; L holds B(t1) ----
  STAGE_A(0);               // A(t0): issued FIRST (FIFO head)
  LOAD_BGLB();              // L = B(t0)
  gAp += 64;                // -> A(t1)
  CVT_WRITE_B(0);           // waits B(t0) gloads -> FIFO also drains A-stages
  if (NT > 1) gB += (size_t)64 * ldnB;   // -> t1
  LOAD_BGLB();              // L = B(t1)
  if (NT > 2) gB += (size_t)64 * ldnB;   // -> t2
  asm volatile("s_waitcnt lgkmcnt(0)" ::: "memory");  // CVT writes landed
  __builtin_amdgcn_s_barrier();

  int buf = 0;
  for (int tt = 0; tt < NT; ++tt) {
    const int bb = buf << 16;
    const int ob = (buf ^ 1) << 16;
    const bool pf = (tt + 1 < NT);

    // head: next-tile A stage only (pure VMEM issue, full-region cover)
    if (pf) { STAGE_A(ob); gAp += 64; }
    __builtin_amdgcn_sched_barrier(0);

    {
      v8bf a[8], b0r[4], b1r[4];
      // first half: 16 ds_reads + 32 MFMA (reads-only lgkm queue)
      LOAD_A(bb, 0);
      LOAD_B(bb, 0, b0r);
      LOAD_B(bb, 1, b1r);
      MFMA_QUAD(0, 0, b0r);
      MFMA_QUAD(0, 1, b1r);
      __builtin_amdgcn_sched_barrier(0);

      // middle: a1 reads (FIFO before writes), CVT writes B(t+1) into ob
      // (implicit vmcnt(4) drains the tile-old B-gloads; A-stages stay),
      // refill L with B(t+2). While this wave does CVT VALU, its SIMD
      // partner runs MFMA.
      LOAD_A(bb, 1);
      if (pf) { CVT_WRITE_B(ob); }
      LOAD_BGLB();
      if (tt + 3 < NT) gB += (size_t)64 * ldnB;
      __builtin_amdgcn_sched_barrier(0);

      // second half: 32 MFMA; gate = lgkmcnt(8) (a1 done, 8 writes behind);
      // the writes retire under this stretch -> exit lgkmcnt(0) free.
      MFMA_QUAD(1, 1, b1r);
      MFMA_QUAD(1, 0, b0r);
    }
    __builtin_amdgcn_sched_barrier(0);

    // exit: FIFO-drain the 4 tile-old A-stages (vmcnt 4A+8B -> 8), keep the
    // 8 fresh B-gloads in flight; lgkm already drained (writes hidden).
    asm volatile("s_waitcnt vmcnt(8) lgkmcnt(0)" ::: "memory");
    __builtin_amdgcn_s_barrier();
    buf ^= 1;
  }

  if (FOLD) {
    // ---- blade-fold epilogue via freed LDS (exactly 256x256 bf16 = 128KB).
#pragma unroll
    for (int mi = 0; mi < 8; ++mi) {
      int lrow = wr * 128 + mi * 16 + kc * 4;
#pragma unroll
      for (int nj = 0; nj < 4; ++nj) {
        int lcol = wn * 64 + nj * 16 + r16;
        float bv = bias[n0 + lcol];
#pragma unroll
        for (int j = 0; j < 4; ++j)
          *(unsigned short*)(ldsc + (lrow + j) * 512 + lcol * 2) =
              f2bf(acc[mi][nj][j] + bv);
      }
    }
    __syncthreads();
    float m3r[64];
#pragma unroll
    for (int p = 0; p < 64; ++p) m3r[p] = m3[p];
    const int cg = (t & 31) * 8;           // group col
    const int rof = (t >> 5);              // 0..15
    unsigned short* ho = (unsigned short*)Cout;
#pragma unroll
    for (int pass = 0; pass < 16; ++pass) {
      int row = pass * 16 + rof;
      uint4 raw = *(const uint4*)(ldsc + row * 512 + cg * 2);
      const unsigned short* rp = (const unsigned short*)&raw;
      float v[8];
#pragma unroll
      for (int p = 0; p < 8; ++p) v[p] = bf2f(rp[p]);
      alignas(16) unsigned short o[8];
#pragma unroll
      for (int j = 0; j < 8; ++j) {
        float s = 0.f;
#pragma unroll
        for (int p = 0; p < 8; ++p) s += v[p] * m3r[p * 8 + j];
        o[j] = f2bf(s);
      }
      *(uint4*)(ho + (size_t)(m0 + row) * N + n0 + cg) = *(const uint4*)o;
    }
    return;
  }

  unsigned short* Pp =
      (unsigned short*)Cout + (SPLITK ? (size_t)bz * M * N : 0);
#pragma unroll
  for (int mi = 0; mi < 8; ++mi) {
    int grow = m0 + wr * 128 + mi * 16 + kc * 4;
#pragma unroll
    for (int nj = 0; nj < 4; ++nj) {
      int gcol = n0 + wn * 64 + nj * 16 + r16;
      float bv = SPLITK ? 0.f : bias[gcol];
#pragma unroll
      for (int j = 0; j < 4; ++j) {
        float v = acc[mi][nj][j] + bv;
        size_t idxo = (size_t)(grow + j) * N + gcol;
        if (OUT_BF16)
          ((unsigned short*)Cout)[idxo] = f2bf(v);
        else if (SPLITK)
          Pp[idxo] = f2bf(v);            // bf16 partial
        else
          ((float*)Cout)[idxo] = v;
      }
    }
  }
#undef STAGE_A
#undef LOAD_BGLB
#undef CVT_WRITE_B
#undef LOAD_A
#undef LOAD_B
#undef MFMA_QUAD
}

// out[i] = sum_s bf16 part[s*MN + i] + bias[i % N], 4 elems/thread, fixed order
__global__ void reduce_splitk_kernel(const unsigned short* __restrict__ part,
                                     const float* __restrict__ bias,
                                     float* __restrict__ out, int MN, int N, int S) {
  int i = (blockIdx.x * 256 + threadIdx.x) * 4;
  float4 s = {0.f, 0.f, 0.f, 0.f};
  for (int k = 0; k < S; ++k) {
    ushort4 v = *(const ushort4*)(part + (size_t)k * MN + i);
    s.x += bf2f(v.x); s.y += bf2f(v.y); s.z += bf2f(v.z); s.w += bf2f(v.w);
  }
  int n = i & (N - 1);
  const float4 bv = *(const float4*)(bias + n);
  s.x += bv.x; s.y += bv.y; s.z += bv.z; s.w += bv.w;
  *(float4*)(out + i) = s;
}

// ---------------- launch ----------------

extern "C" void kernel_launch(void* const* d_in, const int* in_sizes, int n_in,
                              void* d_out, int out_size, void* d_ws, size_t ws_size,
                              hipStream_t stream) {
  const float* x     = (const float*)d_in[0];   // 1024 x 4096
  const float* W_in  = (const float*)d_in[1];   // 4096 x 16384
  const float* b_in  = (const float*)d_in[2];   // 16384
  const float* W_e   = (const float*)d_in[3];   // 8 x 8
  const float* W_out = (const float*)d_in[4];   // 16384 x 2048
  const float* b_out = (const float*)d_in[5];   // 2048
  float* out = (float*)d_out;                   // 1024 x 2048 f32

  char* ws = (char*)d_ws;
  const size_t OFF_M3 = 0;                      // 256 B
  const size_t OFF_X  = 1ull << 20;             // 8 MB   (x bf16)
  const size_t OFF_H  = 10ull << 20;            // 32 MB  (h bf16)
  const size_t OFF_P  = 48ull << 20;            // 32 MB  split-K bf16 partials
  float* m3          = (float*)(ws + OFF_M3);
  unsigned short* xb = (unsigned short*)(ws + OFF_X);
  unsigned short* h  = (unsigned short*)(ws + OFF_H);
  unsigned short* part = (unsigned short*)(ws + OFF_P);

  prep_m3_kernel<<<1, 64, 0, stream>>>(W_e, m3);
  cvt_bf16_kernel<<<2048, 256, 0, stream>>>(x, xb);  // 1024*4096 / (256*8)

  // h = fold(x @ W_in + b_in)  (1024 x 16384, bf16; W staged f32->bf16 and
  // M^3 blade-fold applied in-epilogue)
  gemm256f_kernel<true, false, true><<<dim3(64, 4), 512, 0, stream>>>(
      xb, W_in, b_in, h, 1024, 16384, 4096, 4096, 16384, m3);

  // partials[z] = h @ W_out over K-chunk z  (split-K 8 x 2048, bf16 partials)
  gemm256f_kernel<false, true, false><<<dim3(8, 4, 8), 512, 0, stream>>>(
      h, W_out, nullptr, part, 1024, 2048, 2048, 16384, 2048, nullptr);

  // out = sum_z partials[z] + b_out
  reduce_splitk_kernel<<<2048, 256, 0, stream>>>(part, b_out, out, 1024 * 2048, 2048, 8);
}